// Round 5
// baseline (1639.795 us; speedup 1.0000x reference)
//
#include <hip/hip_runtime.h>

typedef float4 f4;

// ---- ws float-offset layout ----
#define F_S0   0        // 64: per-row W0 scales
#define F_BN0  64       // g[64] be[64] m[64] r[64]
#define F_BN1  320
#define F_BN2  576
#define F_BN3  832      // g[16] be[16] m[16] r[16]
#define F_WQ1  896      // 4096 fp32 [64][64]
#define F_WQ2  4992     // 4096 fp32
#define F_WQ3  9088     // 640 fp32 [10][64]
#define F_WI8  9728     // int8 tiled W0: 196608 B
#define F_WQ0  58880    // fp32 tiled W0: 196608 floats (optional)
#define WS_NEED_F32 ((size_t)(F_WQ0 + 196608) * 4)

struct InPtrs { const float* p[25]; };

// ---------------- prep: fp32 scales/weights/BN consts (np-f32 exact ops) ----------------
__global__ __launch_bounds__(256) void qtfc_prep(InPtrs P, float* __restrict__ wsf, int wf32) {
#pragma clang fp contract(off)
  __shared__ float red[256];
  const int tid = threadIdx.x, b = blockIdx.x;
  if (b < 64) {
    const int row = b;
    const float* W = P.p[1];
    float mx = 0.f;
    for (int k = tid; k < 3072; k += 256) mx = fmaxf(mx, fabsf(W[row * 3072 + k]));
    red[tid] = mx; __syncthreads();
    for (int s = 128; s > 0; s >>= 1) { if (tid < s) red[tid] = fmaxf(red[tid], red[tid + s]); __syncthreads(); }
    const float sv = fmaxf(__fdiv_rn(red[0], 7.f), 1e-8f);
    const int g = row >> 3, jj = row & 7;
    signed char* wi8 = (signed char*)(wsf + F_WI8);
    float* wq0 = wsf + F_WQ0;
    for (int k = tid; k < 3072; k += 256) {
      const float r = rintf(__fdiv_rn(W[row * 3072 + k], sv));
      const int idx = (((g * 96 + (k >> 5)) * 8 + ((k >> 2) & 7)) * 32) + jj * 4 + (k & 3);
      wi8[idx] = (signed char)(int)r;
      if (wf32) wq0[idx] = __fmul_rn(r, sv);
    }
    if (tid == 0) {
      wsf[F_S0 + row] = sv;
      const float gg = P.p[3][row], be = P.p[4][row], m = P.p[5][row], v = P.p[6][row];
      const float rr = __fdiv_rn(1.f, __fsqrt_rn(__fadd_rn(v, 1e-5f)));
      wsf[F_BN0 + row] = gg; wsf[F_BN0 + 64 + row] = be; wsf[F_BN0 + 128 + row] = m; wsf[F_BN0 + 192 + row] = rr;
    }
  } else if (b < 192) {
    const int lay = b >> 6, row = b & 63;   // lay = 1,2
    const float* W = P.p[1 + 6 * lay];
    red[tid] = (tid < 64) ? fabsf(W[row * 64 + tid]) : 0.f; __syncthreads();
    for (int s = 128; s > 0; s >>= 1) { if (tid < s) red[tid] = fmaxf(red[tid], red[tid + s]); __syncthreads(); }
    const float sv = fmaxf(__fdiv_rn(red[0], 7.f), 1e-8f);
    float* wq = wsf + (lay == 1 ? F_WQ1 : F_WQ2);
    if (tid < 64)
      wq[row * 64 + tid] = __fmul_rn(rintf(__fdiv_rn(W[row * 64 + tid], sv)), sv);
    if (tid == 0) {
      const int base = (lay == 1) ? F_BN1 : F_BN2;
      const float gg = P.p[3 + 6 * lay][row], be = P.p[4 + 6 * lay][row];
      const float m = P.p[5 + 6 * lay][row], v = P.p[6 + 6 * lay][row];
      const float rr = __fdiv_rn(1.f, __fsqrt_rn(__fadd_rn(v, 1e-5f)));
      wsf[base + row] = gg; wsf[base + 64 + row] = be; wsf[base + 128 + row] = m; wsf[base + 192 + row] = rr;
    }
  } else {
    const float* W = P.p[19];
    float mx = 0.f;
    for (int k = tid; k < 640; k += 256) mx = fmaxf(mx, fabsf(W[k]));
    red[tid] = mx; __syncthreads();
    for (int s = 128; s > 0; s >>= 1) { if (tid < s) red[tid] = fmaxf(red[tid], red[tid + s]); __syncthreads(); }
    const float sv = fmaxf(__fdiv_rn(red[0], 7.f), 1e-8f);
    for (int k = tid; k < 640; k += 256)
      wsf[F_WQ3 + k] = __fmul_rn(rintf(__fdiv_rn(W[k], sv)), sv);
    if (tid < 10) {
      const float gg = P.p[21][tid], be = P.p[22][tid], m = P.p[23][tid], v = P.p[24][tid];
      const float rr = __fdiv_rn(1.f, __fsqrt_rn(__fadd_rn(v, 1e-5f)));
      wsf[F_BN3 + tid] = gg; wsf[F_BN3 + 16 + tid] = be; wsf[F_BN3 + 32 + tid] = m; wsf[F_BN3 + 48 + tid] = rr;
    }
  }
}

// ---------------- exact-np helpers ----------------
__device__ __forceinline__ float bn_act4(float hv, float g, float be, float m, float r) {
#pragma clang fp contract(off)
  const float bnv = __fadd_rn(__fmul_rn(__fmul_rn(g, __fsub_rn(hv, m)), r), be);
  const float y = fminf(fmaxf(bnv, -1.f), 1.f);
  return __fdiv_rn(rintf(__fmul_rn(y, 7.f)), 7.f);
}
__device__ __forceinline__ float lutq(float v, const float* lut) {
#pragma clang fp contract(off)
  const float y = fminf(fmaxf(v, -1.f), 1.f);
  const float r = rintf(__fmul_rn(y, 127.f));
  return lut[(int)r + 127];   // == __fdiv_rn(r, 127.f), precomputed
}

// swizzle key: bijective on rows {2q+i} AND {q+8i} within a 16-row wave tile
__device__ __forceinline__ int xkey(int row) {
  return ((row >> 1) & 7) ^ ((row & 1) << 2);
}

// wave-private 16x64 FC layer (fp32 exact, ascending-k chain)
__device__ __forceinline__ void layer64w(const float* asrc, float* adst,
                                         const float* __restrict__ wq,
                                         const float* __restrict__ bn,
                                         int rq, int cq, int nch) {
#pragma clang fp contract(off)
  const f4* av4 = (const f4*)asrc;
  f4* ad4 = (f4*)adst;
  const f4* wq4 = (const f4*)wq;
#pragma unroll
  for (int i = 0; i < 2; ++i) {
    const int row = 2 * rq + i;
    f4 av[16];
#pragma unroll
    for (int s = 0; s < 16; ++s) {
      const int pq = ((s & 7) ^ rq) | (s & 8);
      av[s] = av4[row * 16 + pq];
    }
    float af[8];
#pragma unroll
    for (int j = 0; j < 8; ++j) {
      const int ch = 8 * cq + j;
      float a = 0.f;
      if (ch < nch) {
#pragma unroll
        for (int s = 0; s < 16; ++s) {
          const f4 wv = wq4[ch * 16 + s];
          a = __fmaf_rn(av[s].x, wv.x, a);
          a = __fmaf_rn(av[s].y, wv.y, a);
          a = __fmaf_rn(av[s].z, wv.z, a);
          a = __fmaf_rn(av[s].w, wv.w, a);
        }
        af[j] = bn_act4(a, bn[ch], bn[64 + ch], bn[128 + ch], bn[192 + ch]);
      } else af[j] = 0.f;
    }
#pragma unroll
    for (int e = 0; e < 2; ++e) {
      const int lq = 2 * cq + e;
      const int pq = ((lq & 7) ^ rq) | (lq & 8);
      f4 v; v.x = af[4 * e]; v.y = af[4 * e + 1]; v.z = af[4 * e + 2]; v.w = af[4 * e + 3];
      ad4[row * 16 + pq] = v;
    }
  }
}

// ---------------- main: 256 thr (4 waves), wave-private, no barriers ----------------
template<int W8>
__global__ __launch_bounds__(256, 4) void qtfc_main(const float* __restrict__ x,
                                                    const float* __restrict__ wsf,
                                                    float* __restrict__ out) {
#pragma clang fp contract(off)
  __shared__ float smem[4][2304];   // per wave: [0:1024) a1 (xt=[0:512)) | [1024:1280) lut | [1280:2304) a2
  const int tid = threadIdx.x;
  const int w = tid >> 6, l = tid & 63;
  const int rq = l >> 3, cq = l & 7;
  const int row0 = blockIdx.x * 64 + w * 16;   // wave's first global row
  float* R = smem[w];
  float* xt = R;
  float* a1 = R;
  float* lut = R + 1024;
  float* a2 = R + 1280;

  // per-wave LUT init: lut[r+127] = fdiv_rn(r,127)
#pragma unroll
  for (int ii = 0; ii < 4; ++ii) {
    const int idx = ii * 64 + l;
    lut[idx] = __fdiv_rn((float)(idx - 127), 127.f);
  }

  float svj[8];
  if (W8) {
#pragma unroll
    for (int j = 0; j < 8; ++j) svj[j] = wsf[F_S0 + 8 * cq + j];
  }

  // staging: lane l stages rows (l>>3)+8i, k-slot l&7
  const int h0 = l >> 3, sl = l & 7;
  const float* xb[2];
  int stq[2];
  f4 gx[2];
#pragma unroll
  for (int i = 0; i < 2; ++i) {
    const int rloc = h0 + 8 * i;
    xb[i] = x + (long)(row0 + rloc) * 3072 + sl * 4;
    stq[i] = rloc * 8 + (sl ^ xkey(rloc));
    gx[i] = *(const f4*)(xb[i]);
  }

  float acc[2][8], hs[2][8];
#pragma unroll
  for (int i = 0; i < 2; ++i)
#pragma unroll
    for (int j = 0; j < 8; ++j) { acc[i][j] = 0.f; hs[i][j] = 0.f; }

  f4* xt4 = (f4*)xt;
  const f4* wg = (const f4*)(wsf + F_WQ0) + (long)cq * 96 * 64;   // per tile: 64 f4 (8s x 8j)
  const int4* w8g = (const int4*)(wsf + F_WI8) + (long)cq * 96 * 16; // per tile: 16 int4

  const int rdq0 = (2 * rq) * 8;        // row 2rq quad base; key = rq
  const int rdq1 = (2 * rq + 1) * 8;    // row 2rq+1; key = rq^4

#pragma unroll 1
  for (int t = 0; t < 96; ++t) {
    // quantize + stage current tile (wave-private LDS)
#pragma unroll
    for (int i = 0; i < 2; ++i) {
      f4 q;
      q.x = lutq(gx[i].x, lut); q.y = lutq(gx[i].y, lut);
      q.z = lutq(gx[i].z, lut); q.w = lutq(gx[i].w, lut);
      xt4[stq[i]] = q;
    }
    // prefetch next tile's x
    const int tn = (t < 95) ? t + 1 : 95;
#pragma unroll
    for (int i = 0; i < 2; ++i) gx[i] = *(const f4*)(xb[i] + tn * 32);

    if (!W8) {
      const f4* wt = wg + t * 64;
#pragma unroll 1
      for (int s = 0; s < 8; ++s) {
        const f4 xa0 = xt4[rdq0 + (s ^ rq)];
        const f4 xa1 = xt4[rdq1 + (s ^ rq ^ 4)];
        const f4* ws8 = wt + s * 8;
#pragma unroll
        for (int j = 0; j < 8; ++j) {
          const f4 wv = ws8[j];
          acc[0][j] = __fmaf_rn(xa0.x, wv.x, acc[0][j]);
          acc[0][j] = __fmaf_rn(xa0.y, wv.y, acc[0][j]);
          acc[0][j] = __fmaf_rn(xa0.z, wv.z, acc[0][j]);
          acc[0][j] = __fmaf_rn(xa0.w, wv.w, acc[0][j]);
          acc[1][j] = __fmaf_rn(xa1.x, wv.x, acc[1][j]);
          acc[1][j] = __fmaf_rn(xa1.y, wv.y, acc[1][j]);
          acc[1][j] = __fmaf_rn(xa1.z, wv.z, acc[1][j]);
          acc[1][j] = __fmaf_rn(xa1.w, wv.w, acc[1][j]);
        }
      }
    } else {
      const int4* wt = w8g + t * 16;
#pragma unroll 1
      for (int s = 0; s < 8; ++s) {
        const f4 xa0 = xt4[rdq0 + (s ^ rq)];
        const f4 xa1 = xt4[rdq1 + (s ^ rq ^ 4)];
        const int4 da = wt[s * 2], db = wt[s * 2 + 1];
        const int wd[8] = {da.x, da.y, da.z, da.w, db.x, db.y, db.z, db.w};
#pragma unroll
        for (int j = 0; j < 8; ++j) {
          f4 wv;
          wv.x = __fmul_rn((float)((signed char)(wd[j] & 255)), svj[j]);
          wv.y = __fmul_rn((float)((signed char)((wd[j] >> 8) & 255)), svj[j]);
          wv.z = __fmul_rn((float)((signed char)((wd[j] >> 16) & 255)), svj[j]);
          wv.w = __fmul_rn((float)((signed char)((wd[j] >> 24) & 255)), svj[j]);
          acc[0][j] = __fmaf_rn(xa0.x, wv.x, acc[0][j]);
          acc[0][j] = __fmaf_rn(xa0.y, wv.y, acc[0][j]);
          acc[0][j] = __fmaf_rn(xa0.z, wv.z, acc[0][j]);
          acc[0][j] = __fmaf_rn(xa0.w, wv.w, acc[0][j]);
          acc[1][j] = __fmaf_rn(xa1.x, wv.x, acc[1][j]);
          acc[1][j] = __fmaf_rn(xa1.y, wv.y, acc[1][j]);
          acc[1][j] = __fmaf_rn(xa1.z, wv.z, acc[1][j]);
          acc[1][j] = __fmaf_rn(xa1.w, wv.w, acc[1][j]);
        }
      }
    }

    if ((t % 12) == 11) {   // end of KC=384 block: sequential fp32 block-sum combine
#pragma unroll
      for (int i = 0; i < 2; ++i)
#pragma unroll
        for (int j = 0; j < 8; ++j) { hs[i][j] = __fadd_rn(hs[i][j], acc[i][j]); acc[i][j] = 0.f; }
    }
  }

  // ---- layer-0 epilogue: BN + 4-bit act -> a1 (wave-private, swizzled quads) ----
  {
    const float* bn0 = wsf + F_BN0;
    f4* a14 = (f4*)a1;
#pragma unroll
    for (int i = 0; i < 2; ++i) {
      const int row = 2 * rq + i;
      float af[8];
#pragma unroll
      for (int j = 0; j < 8; ++j) {
        const int ch = 8 * cq + j;
        af[j] = bn_act4(hs[i][j], bn0[ch], bn0[64 + ch], bn0[128 + ch], bn0[192 + ch]);
      }
#pragma unroll
      for (int e = 0; e < 2; ++e) {
        const int lq = 2 * cq + e;
        const int pq = ((lq & 7) ^ rq) | (lq & 8);
        f4 v; v.x = af[4 * e]; v.y = af[4 * e + 1]; v.z = af[4 * e + 2]; v.w = af[4 * e + 3];
        a14[row * 16 + pq] = v;
      }
    }
  }

  // ---- layers 1,2 (wave-private) ----
  layer64w(a1, a2, wsf + F_WQ1, wsf + F_BN1, rq, cq, 64);
  layer64w(a2, a1, wsf + F_WQ2, wsf + F_BN2, rq, cq, 64);

  // ---- layer 3: 10 outputs, BN, no act ----
  {
    const f4* a14 = (const f4*)a1;
    const f4* wq3 = (const f4*)(wsf + F_WQ3);
    const float* bn3 = wsf + F_BN3;
#pragma unroll
    for (int i = 0; i < 2; ++i) {
      const int row = 2 * rq + i;
      f4 av[16];
#pragma unroll
      for (int s = 0; s < 16; ++s) {
        const int pq = ((s & 7) ^ rq) | (s & 8);
        av[s] = a14[row * 16 + pq];
      }
#pragma unroll
      for (int j = 0; j < 8; ++j) {
        const int ch = 8 * cq + j;
        if (ch < 10) {
          float a = 0.f;
#pragma unroll
          for (int s = 0; s < 16; ++s) {
            const f4 wv = wq3[ch * 16 + s];
            a = __fmaf_rn(av[s].x, wv.x, a);
            a = __fmaf_rn(av[s].y, wv.y, a);
            a = __fmaf_rn(av[s].z, wv.z, a);
            a = __fmaf_rn(av[s].w, wv.w, a);
          }
          const float o = __fadd_rn(__fmul_rn(__fmul_rn(bn3[ch], __fsub_rn(a, bn3[32 + ch])), bn3[48 + ch]), bn3[16 + ch]);
          out[(long)(row0 + row) * 10 + ch] = o;
        }
      }
    }
  }
}

extern "C" void kernel_launch(void* const* d_in, const int* in_sizes, int n_in,
                              void* d_out, int out_size, void* d_ws, size_t ws_size,
                              hipStream_t stream) {
  (void)in_sizes; (void)n_in; (void)out_size;
  InPtrs P;
  for (int i = 0; i < 25; ++i) P.p[i] = (const float*)d_in[i];
  float* wsf = (float*)d_ws;
  const int wf32 = (ws_size >= WS_NEED_F32) ? 1 : 0;
  qtfc_prep<<<193, 256, 0, stream>>>(P, wsf, wf32);
  if (wf32)
    qtfc_main<0><<<512, 256, 0, stream>>>((const float*)d_in[0], wsf, (float*)d_out);
  else
    qtfc_main<1><<<512, 256, 0, stream>>>((const float*)d_in[0], wsf, (float*)d_out);
}